// Round 8
// baseline (169.638 us; speedup 1.0000x reference)
//
#include <hip/hip_runtime.h>

#define N_CH 128

typedef short bf16x8 __attribute__((ext_vector_type(8)));
typedef float f32x4 __attribute__((ext_vector_type(4)));

__device__ __forceinline__ unsigned short f2bf(float f) {
    unsigned int u = __float_as_uint(f);
    unsigned int r = (u + 0x7fffu + ((u >> 16) & 1u)) >> 16;
    return (unsigned short)r;
}
__device__ __forceinline__ unsigned int pkbf(float a, float b) {
    return (unsigned int)f2bf(a) | ((unsigned int)f2bf(b) << 16);
}
__device__ __forceinline__ float bflo(unsigned int v) { return __uint_as_float(v << 16); }
__device__ __forceinline__ float bfhi(unsigned int v) { return __uint_as_float(v & 0xffff0000u); }

// ---------------- fused init: zero deg | prep Bt1/Bt2 | cast x -> bf16 node-major --
// Bt1: [128 n][256 k]  (k<128 from Ws1, k>=128 from Wn1)
// Bt2: [128 n][128 k]  (n<64 from Ws2 -> out half, n>=64 from Wn2 -> p2 half)
__global__ __launch_bounds__(256) void k_init(const float* __restrict__ x,
                                              const float* __restrict__ Ws1,
                                              const float* __restrict__ Wn1,
                                              const float* __restrict__ Ws2,
                                              const float* __restrict__ Wn2,
                                              int* __restrict__ deg,
                                              unsigned short* __restrict__ Bt1,
                                              unsigned short* __restrict__ Bt2,
                                              uint4* __restrict__ xb4,
                                              int ndeg4, int nxq) {
    int b = blockIdx.x, t = threadIdx.x;
    if (b < 49) {
        int i = b * 256 + t;
        if (i < ndeg4) ((uint4*)deg)[i] = make_uint4(0, 0, 0, 0);
    } else if (b < 241) {
        int idx = (b - 49) * 256 + t;
        if (idx < 128 * 256) {  // Bt1
            int n = idx >> 8, k = idx & 255;
            float v = (k < 128) ? Ws1[k * 128 + n] : Wn1[(k - 128) * 128 + n];
            Bt1[idx] = f2bf(v);
        } else {  // Bt2 (16384 elems)
            int j = idx - 128 * 256;
            int n = j >> 7, k = j & 127;
            float v = (n < 64) ? Ws2[k * 64 + n] : Wn2[k * 64 + (n - 64)];
            Bt2[j] = f2bf(v);
        }
    } else {
        int q = (b - 241) * 256 + t;
        if (q < nxq) {
            const float4* xf = (const float4*)x;
            float4 f0 = xf[2 * q], f1 = xf[2 * q + 1];
            uint4 o;
            o.x = pkbf(f0.x, f0.y); o.y = pkbf(f0.z, f0.w);
            o.z = pkbf(f1.x, f1.y); o.w = pkbf(f1.z, f1.w);
            xb4[q] = o;  // node-major [N][16 uint4]
        }
    }
}

// ---------------- degree histogram + per-edge rank (atomic return value) ----------
__global__ __launch_bounds__(256) void k_deg_rank(const int* __restrict__ dst,
                                                  int* __restrict__ deg,
                                                  int* __restrict__ rank, int e) {
    int i = blockIdx.x * 256 + threadIdx.x;
    if (i < e) {
        int r = atomicAdd(&deg[dst[i]], 1);
        rank[i] = r;
    }
}

// ---------------- single-pass-per-block exclusive scan: deg -> row_start ----------
__global__ __launch_bounds__(256) void k_scan_final(const int* __restrict__ deg,
                                                    int* __restrict__ row_start, int n) {
    __shared__ int sm[256];
    int t = threadIdx.x;
    int b = blockIdx.x;
    int i = b * 256 + t;
    // prefix reduction over earlier blocks' deg (L2-resident)
    int acc = 0;
    for (int j = t; j < b * 256; j += 256) acc += deg[j];
    sm[t] = acc;
    __syncthreads();
    for (int s = 128; s > 0; s >>= 1) {
        if (t < s) sm[t] += sm[t + s];
        __syncthreads();
    }
    int base = sm[0];
    __syncthreads();
    // local inclusive scan
    int v = (i < n) ? deg[i] : 0;
    sm[t] = v;
    __syncthreads();
    for (int off = 1; off < 256; off <<= 1) {
        int add = (t >= off) ? sm[t - off] : 0;
        __syncthreads();
        sm[t] += add;
        __syncthreads();
    }
    if (i < n) row_start[i] = base + sm[t] - v;
}

// ---------------- CSR fill — NO atomics (rank precomputed) ----------------
__global__ __launch_bounds__(256) void k_fill_csr(const int* __restrict__ src,
                                                  const int* __restrict__ dst,
                                                  const int* __restrict__ rank,
                                                  const int* __restrict__ row_start,
                                                  int* __restrict__ csr_src, int e) {
    int i = blockIdx.x * 256 + threadIdx.x;
    if (i < e) {
        int d = dst[i];
        csr_src[row_start[d] + rank[i]] = src[i];
    }
}

// ---------------- neighbor-mean of x (bf16): xagg = mean(xb[neigh]) ----------------
// one wave per node; 4 quarters of 16 lanes each gather a different neighbor row
// (16 lanes x uint4 = 256B row); 4-deep unroll -> 16 rows in flight per wave.
__global__ __launch_bounds__(256) void k_aggx(const uint4* __restrict__ xb4,
                                              uint4* __restrict__ xagg4,
                                              const int* __restrict__ row_start,
                                              const int* __restrict__ deg,
                                              const int* __restrict__ csr, int n) {
    int gw = (blockIdx.x * 256 + threadIdx.x) >> 6;
    int lane = threadIdx.x & 63;
    if (gw >= n) return;
    int start = row_start[gw];
    int cnt = deg[gw];
    const int q = lane >> 4;
    const int cl = lane & 15;
    float a0 = 0.f, a1 = 0.f, a2 = 0.f, a3 = 0.f, a4 = 0.f, a5 = 0.f, a6 = 0.f, a7 = 0.f;
    int i = 0;
    for (; i + 16 <= cnt; i += 16) {
        int e0 = csr[start + i + q];
        int e1 = csr[start + i + 4 + q];
        int e2 = csr[start + i + 8 + q];
        int e3 = csr[start + i + 12 + q];
        uint4 v0 = xb4[e0 * 16 + cl];
        uint4 v1 = xb4[e1 * 16 + cl];
        uint4 v2 = xb4[e2 * 16 + cl];
        uint4 v3 = xb4[e3 * 16 + cl];
        a0 += bflo(v0.x) + bflo(v1.x) + bflo(v2.x) + bflo(v3.x);
        a1 += bfhi(v0.x) + bfhi(v1.x) + bfhi(v2.x) + bfhi(v3.x);
        a2 += bflo(v0.y) + bflo(v1.y) + bflo(v2.y) + bflo(v3.y);
        a3 += bfhi(v0.y) + bfhi(v1.y) + bfhi(v2.y) + bfhi(v3.y);
        a4 += bflo(v0.z) + bflo(v1.z) + bflo(v2.z) + bflo(v3.z);
        a5 += bfhi(v0.z) + bfhi(v1.z) + bfhi(v2.z) + bfhi(v3.z);
        a6 += bflo(v0.w) + bflo(v1.w) + bflo(v2.w) + bflo(v3.w);
        a7 += bfhi(v0.w) + bfhi(v1.w) + bfhi(v2.w) + bfhi(v3.w);
    }
    if (i + 8 <= cnt) {
        int e0 = csr[start + i + q];
        int e1 = csr[start + i + 4 + q];
        uint4 v0 = xb4[e0 * 16 + cl];
        uint4 v1 = xb4[e1 * 16 + cl];
        a0 += bflo(v0.x) + bflo(v1.x); a1 += bfhi(v0.x) + bfhi(v1.x);
        a2 += bflo(v0.y) + bflo(v1.y); a3 += bfhi(v0.y) + bfhi(v1.y);
        a4 += bflo(v0.z) + bflo(v1.z); a5 += bfhi(v0.z) + bfhi(v1.z);
        a6 += bflo(v0.w) + bflo(v1.w); a7 += bfhi(v0.w) + bfhi(v1.w);
        i += 8;
    }
    for (; i < cnt; i += 4) {
        int nbi = i + q;
        if (nbi < cnt) {
            uint4 va = xb4[csr[start + nbi] * 16 + cl];
            a0 += bflo(va.x); a1 += bfhi(va.x);
            a2 += bflo(va.y); a3 += bfhi(va.y);
            a4 += bflo(va.z); a5 += bfhi(va.z);
            a6 += bflo(va.w); a7 += bfhi(va.w);
        }
    }
    // combine the 4 quarters
    a0 += __shfl_xor(a0, 16); a0 += __shfl_xor(a0, 32);
    a1 += __shfl_xor(a1, 16); a1 += __shfl_xor(a1, 32);
    a2 += __shfl_xor(a2, 16); a2 += __shfl_xor(a2, 32);
    a3 += __shfl_xor(a3, 16); a3 += __shfl_xor(a3, 32);
    a4 += __shfl_xor(a4, 16); a4 += __shfl_xor(a4, 32);
    a5 += __shfl_xor(a5, 16); a5 += __shfl_xor(a5, 32);
    a6 += __shfl_xor(a6, 16); a6 += __shfl_xor(a6, 32);
    a7 += __shfl_xor(a7, 16); a7 += __shfl_xor(a7, 32);

    float inv = 1.0f / fmaxf((float)cnt, 1.0f);
    if (q == 0) {
        uint4 o;
        o.x = pkbf(inv * a0, inv * a1);
        o.y = pkbf(inv * a2, inv * a3);
        o.z = pkbf(inv * a4, inv * a5);
        o.w = pkbf(inv * a6, inv * a7);
        xagg4[gw * 16 + cl] = o;
    }
}

// ---------------- gemm1: h1b = relu([xb | xagg] @ Bt1^T + b1), K=256 ----------------
// A staged in LDS (swizzled); B direct from global (L2-resident).
__global__ __launch_bounds__(256) void k_gemm1(const uint4* __restrict__ xb4,
                                               const uint4* __restrict__ xagg4,
                                               const unsigned short* __restrict__ Bt1,
                                               const float* __restrict__ b1,
                                               unsigned short* __restrict__ h1b, int M) {
    __shared__ unsigned short As[64][256];
    const int m0 = blockIdx.x * 64;
    const int tid = threadIdx.x;
    const int w = tid >> 6;
    const int l = tid & 63;

    for (int p = tid; p < 2048; p += 256) {
        int row = p >> 5, c = p & 31;
        int gr = m0 + row;
        uint4 v = make_uint4(0, 0, 0, 0);
        if (gr < M) v = (c < 16) ? xb4[gr * 16 + c] : xagg4[gr * 16 + (c - 16)];
        *(uint4*)&As[row][(c ^ (row & 7)) * 8] = v;
    }
    __syncthreads();

    const int fr = l & 15;
    const int kq = l >> 4;
    f32x4 acc[2][4] = {};
#pragma unroll
    for (int kt = 0; kt < 8; ++kt) {
        bf16x8 bfr[2];
#pragma unroll
        for (int ct = 0; ct < 2; ++ct) {
            int nn = w * 32 + ct * 16 + fr;
            bfr[ct] = *(const bf16x8*)&Bt1[nn * 256 + kt * 32 + kq * 8];
        }
        bf16x8 af[4];
#pragma unroll
        for (int rt = 0; rt < 4; ++rt) {
            int row = rt * 16 + fr;
            int c = (kt * 4 + kq) ^ (row & 7);
            af[rt] = *(bf16x8*)&As[row][c * 8];
        }
#pragma unroll
        for (int ct = 0; ct < 2; ++ct)
#pragma unroll
            for (int rt = 0; rt < 4; ++rt)
                acc[ct][rt] = __builtin_amdgcn_mfma_f32_16x16x32_bf16(af[rt], bfr[ct],
                                                                      acc[ct][rt], 0, 0, 0);
    }

#pragma unroll
    for (int ct = 0; ct < 2; ++ct) {
        int col = w * 32 + ct * 16 + fr;
        float bv = b1[col];
#pragma unroll
        for (int rt = 0; rt < 4; ++rt) {
#pragma unroll
            for (int j = 0; j < 4; ++j) {
                int row = m0 + rt * 16 + (l >> 4) * 4 + j;
                if (row < M) h1b[row * 128 + col] = f2bf(fmaxf(acc[ct][rt][j] + bv, 0.f));
            }
        }
    }
}

// ---------------- gemm2: [out | p2] = h1b @ Bt2^T (+b2 on out), K=128 ---------------
__global__ __launch_bounds__(256) void k_gemm2(const unsigned short* __restrict__ h1b,
                                               const unsigned short* __restrict__ Bt2,
                                               const float* __restrict__ b2,
                                               float* __restrict__ out,
                                               unsigned short* __restrict__ p2, int M) {
    __shared__ unsigned short As[64][128];
    const int m0 = blockIdx.x * 64;
    const int tid = threadIdx.x;
    const int w = tid >> 6;
    const int l = tid & 63;

    const uint4* A4 = (const uint4*)h1b;
    for (int p = tid; p < 1024; p += 256) {
        int row = p >> 4, c = p & 15;
        int gr = m0 + row;
        uint4 v = make_uint4(0, 0, 0, 0);
        if (gr < M) v = A4[gr * 16 + c];
        *(uint4*)&As[row][(c ^ (row & 7)) * 8] = v;
    }
    __syncthreads();

    const int fr = l & 15;
    const int kq = l >> 4;
    f32x4 acc[2][4] = {};
#pragma unroll
    for (int kt = 0; kt < 4; ++kt) {
        bf16x8 bfr[2];
#pragma unroll
        for (int ct = 0; ct < 2; ++ct) {
            int nn = w * 32 + ct * 16 + fr;
            bfr[ct] = *(const bf16x8*)&Bt2[nn * 128 + kt * 32 + kq * 8];
        }
        bf16x8 af[4];
#pragma unroll
        for (int rt = 0; rt < 4; ++rt) {
            int row = rt * 16 + fr;
            int c = (kt * 4 + kq) ^ (row & 7);
            af[rt] = *(bf16x8*)&As[row][c * 8];
        }
#pragma unroll
        for (int ct = 0; ct < 2; ++ct)
#pragma unroll
            for (int rt = 0; rt < 4; ++rt)
                acc[ct][rt] = __builtin_amdgcn_mfma_f32_16x16x32_bf16(af[rt], bfr[ct],
                                                                      acc[ct][rt], 0, 0, 0);
    }

#pragma unroll
    for (int ct = 0; ct < 2; ++ct) {
        int col = w * 32 + ct * 16 + fr;
        bool isS = col < 64;  // wave-uniform per 16-col tile
        float bv = isS ? b2[col] : 0.f;
#pragma unroll
        for (int rt = 0; rt < 4; ++rt) {
#pragma unroll
            for (int j = 0; j < 4; ++j) {
                int row = m0 + rt * 16 + (l >> 4) * 4 + j;
                if (row < M) {
                    float v = acc[ct][rt][j];
                    if (isS) out[row * 64 + col] = v + bv;
                    else p2[row * 64 + (col - 64)] = f2bf(v);
                }
            }
        }
    }
}

// ---------------- layer-2 aggregation: out += mean_neigh(p2) (64 ch bf16) ----------
// 8 groups of 8 lanes; each group gathers one 128B row via uint4 (8 rows/instr).
__global__ __launch_bounds__(256) void k_agg2_add(const unsigned int* __restrict__ p,
                                                  float* __restrict__ out,
                                                  const int* __restrict__ row_start,
                                                  const int* __restrict__ deg,
                                                  const int* __restrict__ csr, int n) {
    int gw = (blockIdx.x * 256 + threadIdx.x) >> 6;
    int lane = threadIdx.x & 63;
    if (gw >= n) return;
    int start = row_start[gw];
    int cnt = deg[gw];
    const int g = lane >> 3;
    const int cl = lane & 7;
    float a0 = 0.f, a1 = 0.f, a2 = 0.f, a3 = 0.f, a4 = 0.f, a5 = 0.f, a6 = 0.f, a7 = 0.f;
    int i = 0;
    for (; i + 16 <= cnt; i += 16) {
        int e0 = csr[start + i + g];
        int e1 = csr[start + i + 8 + g];
        uint4 v0 = *(const uint4*)&p[e0 * 32 + cl * 4];
        uint4 v1 = *(const uint4*)&p[e1 * 32 + cl * 4];
        a0 += bflo(v0.x) + bflo(v1.x); a1 += bfhi(v0.x) + bfhi(v1.x);
        a2 += bflo(v0.y) + bflo(v1.y); a3 += bfhi(v0.y) + bfhi(v1.y);
        a4 += bflo(v0.z) + bflo(v1.z); a5 += bfhi(v0.z) + bfhi(v1.z);
        a6 += bflo(v0.w) + bflo(v1.w); a7 += bfhi(v0.w) + bfhi(v1.w);
    }
    for (; i < cnt; i += 8) {
        int nbi = i + g;
        if (nbi < cnt) {
            int ia = csr[start + nbi];
            uint4 va = *(const uint4*)&p[ia * 32 + cl * 4];
            a0 += bflo(va.x); a1 += bfhi(va.x);
            a2 += bflo(va.y); a3 += bfhi(va.y);
            a4 += bflo(va.z); a5 += bfhi(va.z);
            a6 += bflo(va.w); a7 += bfhi(va.w);
        }
    }
    a0 += __shfl_xor(a0, 8); a0 += __shfl_xor(a0, 16); a0 += __shfl_xor(a0, 32);
    a1 += __shfl_xor(a1, 8); a1 += __shfl_xor(a1, 16); a1 += __shfl_xor(a1, 32);
    a2 += __shfl_xor(a2, 8); a2 += __shfl_xor(a2, 16); a2 += __shfl_xor(a2, 32);
    a3 += __shfl_xor(a3, 8); a3 += __shfl_xor(a3, 16); a3 += __shfl_xor(a3, 32);
    a4 += __shfl_xor(a4, 8); a4 += __shfl_xor(a4, 16); a4 += __shfl_xor(a4, 32);
    a5 += __shfl_xor(a5, 8); a5 += __shfl_xor(a5, 16); a5 += __shfl_xor(a5, 32);
    a6 += __shfl_xor(a6, 8); a6 += __shfl_xor(a6, 16); a6 += __shfl_xor(a6, 32);
    a7 += __shfl_xor(a7, 8); a7 += __shfl_xor(a7, 16); a7 += __shfl_xor(a7, 32);
    float inv = 1.0f / fmaxf((float)cnt, 1.0f);
    if (g == 0) {
        float4 oa = *(const float4*)&out[gw * 64 + cl * 8];
        float4 ob = *(const float4*)&out[gw * 64 + cl * 8 + 4];
        oa.x += inv * a0; oa.y += inv * a1; oa.z += inv * a2; oa.w += inv * a3;
        ob.x += inv * a4; ob.y += inv * a5; ob.z += inv * a6; ob.w += inv * a7;
        *(float4*)&out[gw * 64 + cl * 8] = oa;
        *(float4*)&out[gw * 64 + cl * 8 + 4] = ob;
    }
}

extern "C" void kernel_launch(void* const* d_in, const int* in_sizes, int n_in,
                              void* d_out, int out_size, void* d_ws, size_t ws_size,
                              hipStream_t stream) {
    const float* x   = (const float*)d_in[0];
    const int*   src = (const int*)d_in[1];
    const int*   dst = (const int*)d_in[2];
    const float* Ws1 = (const float*)d_in[3];
    const float* Wn1 = (const float*)d_in[4];
    const float* b1  = (const float*)d_in[5];
    const float* Ws2 = (const float*)d_in[6];
    const float* Wn2 = (const float*)d_in[7];
    const float* b2  = (const float*)d_in[8];
    float* out = (float*)d_out;
    const int N = in_sizes[0] / N_CH;  // 50000
    const int E = in_sizes[1];         // 800000

    // workspace layout (256B-aligned). rank dead after fill_csr; xagg aliases it.
    char* ws = (char*)d_ws;
    int* deg       = (int*)(ws + 0);          // N ints -> 200704
    int* row_start = (int*)(ws + 200704);     // N ints -> 401408
    int* csr_src   = (int*)(ws + 402432);     // E ints -> 3602432 (persists)
    int* rank      = (int*)(ws + 3602432);    // E ints (dead after fill_csr)
    unsigned short* xagg = (unsigned short*)(ws + 3602432);  // bf16 [N][128] (aliases rank)
    unsigned short* xb  = (unsigned short*)(ws + 16402432);  // bf16 [N][128] node-major
    unsigned short* h1b = (unsigned short*)(ws + 29202432);  // bf16 [N][128]
    unsigned short* p2  = (unsigned short*)(ws + 42002432);  // bf16 [N][64]
    unsigned short* Bt1 = (unsigned short*)(ws + 48402432);  // [128][256] 64KB
    unsigned short* Bt2 = (unsigned short*)(ws + 48467968);  // [128][128] 32KB

    const int eb = (E + 255) / 256;   // 3125
    const int nb = (N + 255) / 256;   // 196
    const int ndeg4 = (N + 3) / 4;    // 12500
    const int nxq = N * 16;           // 800000

    k_init<<<241 + (nxq + 255) / 256, 256, 0, stream>>>(x, Ws1, Wn1, Ws2, Wn2, deg, Bt1, Bt2,
                                                        (uint4*)xb, ndeg4, nxq);
    k_deg_rank<<<eb, 256, 0, stream>>>(dst, deg, rank, E);
    k_scan_final<<<nb, 256, 0, stream>>>(deg, row_start, N);
    k_fill_csr<<<eb, 256, 0, stream>>>(src, dst, rank, row_start, csr_src, E);

    k_aggx<<<(N + 3) / 4, 256, 0, stream>>>((const uint4*)xb, (uint4*)xagg, row_start, deg,
                                            csr_src, N);

    const int gb = (N + 63) / 64;  // 782
    k_gemm1<<<gb, 256, 0, stream>>>((const uint4*)xb, (const uint4*)xagg, Bt1, b1, h1b, N);
    k_gemm2<<<gb, 256, 0, stream>>>(h1b, Bt2, b2, out, p2, N);
    k_agg2_add<<<(N + 3) / 4, 256, 0, stream>>>((const unsigned int*)p2, out, row_start, deg,
                                                csr_src, N);
}

// Round 9
// 153.708 us; speedup vs baseline: 1.1036x; 1.1036x over previous
//
#include <hip/hip_runtime.h>

#define N_CH 128

typedef short bf16x8 __attribute__((ext_vector_type(8)));
typedef float f32x4 __attribute__((ext_vector_type(4)));

__device__ __forceinline__ unsigned short f2bf(float f) {
    unsigned int u = __float_as_uint(f);
    unsigned int r = (u + 0x7fffu + ((u >> 16) & 1u)) >> 16;
    return (unsigned short)r;
}
__device__ __forceinline__ unsigned int pkbf(float a, float b) {
    return (unsigned int)f2bf(a) | ((unsigned int)f2bf(b) << 16);
}
__device__ __forceinline__ float bflo(unsigned int v) { return __uint_as_float(v << 16); }
__device__ __forceinline__ float bfhi(unsigned int v) { return __uint_as_float(v & 0xffff0000u); }

// ---------------- zero deg (runtime small-fill path is pathologically slow) --------
__global__ __launch_bounds__(256) void k_zero(uint4* __restrict__ p, int n4) {
    int i = blockIdx.x * 256 + threadIdx.x;
    if (i < n4) p[i] = make_uint4(0, 0, 0, 0);
}

// ---------------- fused init: prep Bt1/Bt2 | cast x -> bf16 | edge deg+rank --------
// Bt1: [128 n][256 k]  (k<128 from Ws1, k>=128 from Wn1)
// Bt2: [128 n][128 k]  (n<64 from Ws2 -> out half, n>=64 from Wn2 -> p2 half)
// Edge blocks (atomic-latency-bound) co-schedule with cast blocks (BW-bound).
__global__ __launch_bounds__(256) void k_initdeg(const float* __restrict__ x,
                                                 const float* __restrict__ Ws1,
                                                 const float* __restrict__ Wn1,
                                                 const float* __restrict__ Ws2,
                                                 const float* __restrict__ Wn2,
                                                 unsigned short* __restrict__ Bt1,
                                                 unsigned short* __restrict__ Bt2,
                                                 uint4* __restrict__ xb4, int nxq, int nxb,
                                                 const int* __restrict__ dst,
                                                 int* __restrict__ deg,
                                                 int* __restrict__ rank, int e) {
    int b = blockIdx.x, t = threadIdx.x;
    if (b < 192) {
        int idx = b * 256 + t;
        if (idx < 128 * 256) {  // Bt1
            int n = idx >> 8, k = idx & 255;
            float v = (k < 128) ? Ws1[k * 128 + n] : Wn1[(k - 128) * 128 + n];
            Bt1[idx] = f2bf(v);
        } else {  // Bt2 (16384 elems)
            int j = idx - 128 * 256;
            int n = j >> 7, k = j & 127;
            float v = (n < 64) ? Ws2[k * 64 + n] : Wn2[k * 64 + (n - 64)];
            Bt2[j] = f2bf(v);
        }
    } else if (b < 192 + nxb) {
        int q = (b - 192) * 256 + t;
        if (q < nxq) {
            const float4* xf = (const float4*)x;
            float4 f0 = xf[2 * q], f1 = xf[2 * q + 1];
            uint4 o;
            o.x = pkbf(f0.x, f0.y); o.y = pkbf(f0.z, f0.w);
            o.z = pkbf(f1.x, f1.y); o.w = pkbf(f1.z, f1.w);
            xb4[q] = o;  // node-major [N][16 uint4]
        }
    } else {
        int i = (b - 192 - nxb) * 256 + t;
        if (i < e) {
            int r = atomicAdd(&deg[dst[i]], 1);
            rank[i] = r;
        }
    }
}

// ---------------- scan step 1: per-block sums (coalesced) ----------------
__global__ __launch_bounds__(256) void k_block_reduce(const int* __restrict__ deg,
                                                      int* __restrict__ bsum, int n) {
    __shared__ int sm[256];
    int i = blockIdx.x * 256 + threadIdx.x;
    sm[threadIdx.x] = (i < n) ? deg[i] : 0;
    __syncthreads();
    for (int s = 128; s > 0; s >>= 1) {
        if (threadIdx.x < s) sm[threadIdx.x] += sm[threadIdx.x + s];
        __syncthreads();
    }
    if (threadIdx.x == 0) bsum[blockIdx.x] = sm[0];
}

// ---------------- scan step 2: base = sum(bsum[0..b)) (1 load/thread) + local scan -
__global__ __launch_bounds__(256) void k_scan_final(const int* __restrict__ deg,
                                                    const int* __restrict__ bsum,
                                                    int* __restrict__ row_start,
                                                    int n, int nb) {
    __shared__ int sm[256];
    __shared__ int sbase;
    int t = threadIdx.x;
    int b = blockIdx.x;
    int i = b * 256 + t;
    // reduce prefix of block sums (nb <= 256 -> one load per thread)
    sm[t] = (t < b && t < nb) ? bsum[t] : 0;
    __syncthreads();
    for (int s = 128; s > 0; s >>= 1) {
        if (t < s) sm[t] += sm[t + s];
        __syncthreads();
    }
    if (t == 0) sbase = sm[0];
    __syncthreads();
    int base = sbase;
    __syncthreads();
    // local inclusive scan
    int v = (i < n) ? deg[i] : 0;
    sm[t] = v;
    __syncthreads();
    for (int off = 1; off < 256; off <<= 1) {
        int add = (t >= off) ? sm[t - off] : 0;
        __syncthreads();
        sm[t] += add;
        __syncthreads();
    }
    if (i < n) row_start[i] = base + sm[t] - v;
}

// ---------------- CSR fill — NO atomics (rank precomputed) ----------------
__global__ __launch_bounds__(256) void k_fill_csr(const int* __restrict__ src,
                                                  const int* __restrict__ dst,
                                                  const int* __restrict__ rank,
                                                  const int* __restrict__ row_start,
                                                  int* __restrict__ csr_src, int e) {
    int i = blockIdx.x * 256 + threadIdx.x;
    if (i < e) {
        int d = dst[i];
        csr_src[row_start[d] + rank[i]] = src[i];
    }
}

// ---------------- neighbor-mean of x (bf16): xagg = mean(xb[neigh]) ----------------
// one wave per node; 4 quarters of 16 lanes each gather a different neighbor row
// (16 lanes x uint4 = 256B row); 4-deep unroll -> 16 rows in flight per wave.
__global__ __launch_bounds__(256) void k_aggx(const uint4* __restrict__ xb4,
                                              uint4* __restrict__ xagg4,
                                              const int* __restrict__ row_start,
                                              const int* __restrict__ deg,
                                              const int* __restrict__ csr, int n) {
    int gw = (blockIdx.x * 256 + threadIdx.x) >> 6;
    int lane = threadIdx.x & 63;
    if (gw >= n) return;
    int start = row_start[gw];
    int cnt = deg[gw];
    const int q = lane >> 4;
    const int cl = lane & 15;
    float a0 = 0.f, a1 = 0.f, a2 = 0.f, a3 = 0.f, a4 = 0.f, a5 = 0.f, a6 = 0.f, a7 = 0.f;
    int i = 0;
    for (; i + 16 <= cnt; i += 16) {
        int e0 = csr[start + i + q];
        int e1 = csr[start + i + 4 + q];
        int e2 = csr[start + i + 8 + q];
        int e3 = csr[start + i + 12 + q];
        uint4 v0 = xb4[e0 * 16 + cl];
        uint4 v1 = xb4[e1 * 16 + cl];
        uint4 v2 = xb4[e2 * 16 + cl];
        uint4 v3 = xb4[e3 * 16 + cl];
        a0 += bflo(v0.x) + bflo(v1.x) + bflo(v2.x) + bflo(v3.x);
        a1 += bfhi(v0.x) + bfhi(v1.x) + bfhi(v2.x) + bfhi(v3.x);
        a2 += bflo(v0.y) + bflo(v1.y) + bflo(v2.y) + bflo(v3.y);
        a3 += bfhi(v0.y) + bfhi(v1.y) + bfhi(v2.y) + bfhi(v3.y);
        a4 += bflo(v0.z) + bflo(v1.z) + bflo(v2.z) + bflo(v3.z);
        a5 += bfhi(v0.z) + bfhi(v1.z) + bfhi(v2.z) + bfhi(v3.z);
        a6 += bflo(v0.w) + bflo(v1.w) + bflo(v2.w) + bflo(v3.w);
        a7 += bfhi(v0.w) + bfhi(v1.w) + bfhi(v2.w) + bfhi(v3.w);
    }
    if (i + 8 <= cnt) {
        int e0 = csr[start + i + q];
        int e1 = csr[start + i + 4 + q];
        uint4 v0 = xb4[e0 * 16 + cl];
        uint4 v1 = xb4[e1 * 16 + cl];
        a0 += bflo(v0.x) + bflo(v1.x); a1 += bfhi(v0.x) + bfhi(v1.x);
        a2 += bflo(v0.y) + bflo(v1.y); a3 += bfhi(v0.y) + bfhi(v1.y);
        a4 += bflo(v0.z) + bflo(v1.z); a5 += bfhi(v0.z) + bfhi(v1.z);
        a6 += bflo(v0.w) + bflo(v1.w); a7 += bfhi(v0.w) + bfhi(v1.w);
        i += 8;
    }
    for (; i < cnt; i += 4) {
        int nbi = i + q;
        if (nbi < cnt) {
            uint4 va = xb4[csr[start + nbi] * 16 + cl];
            a0 += bflo(va.x); a1 += bfhi(va.x);
            a2 += bflo(va.y); a3 += bfhi(va.y);
            a4 += bflo(va.z); a5 += bfhi(va.z);
            a6 += bflo(va.w); a7 += bfhi(va.w);
        }
    }
    // combine the 4 quarters
    a0 += __shfl_xor(a0, 16); a0 += __shfl_xor(a0, 32);
    a1 += __shfl_xor(a1, 16); a1 += __shfl_xor(a1, 32);
    a2 += __shfl_xor(a2, 16); a2 += __shfl_xor(a2, 32);
    a3 += __shfl_xor(a3, 16); a3 += __shfl_xor(a3, 32);
    a4 += __shfl_xor(a4, 16); a4 += __shfl_xor(a4, 32);
    a5 += __shfl_xor(a5, 16); a5 += __shfl_xor(a5, 32);
    a6 += __shfl_xor(a6, 16); a6 += __shfl_xor(a6, 32);
    a7 += __shfl_xor(a7, 16); a7 += __shfl_xor(a7, 32);

    float inv = 1.0f / fmaxf((float)cnt, 1.0f);
    if (q == 0) {
        uint4 o;
        o.x = pkbf(inv * a0, inv * a1);
        o.y = pkbf(inv * a2, inv * a3);
        o.z = pkbf(inv * a4, inv * a5);
        o.w = pkbf(inv * a6, inv * a7);
        xagg4[gw * 16 + cl] = o;
    }
}

// ---------------- gemm1: h1b = relu([xb | xagg] @ Bt1^T + b1), K=256 ----------------
__global__ __launch_bounds__(256) void k_gemm1(const uint4* __restrict__ xb4,
                                               const uint4* __restrict__ xagg4,
                                               const unsigned short* __restrict__ Bt1,
                                               const float* __restrict__ b1,
                                               unsigned short* __restrict__ h1b, int M) {
    __shared__ unsigned short As[64][256];
    const int m0 = blockIdx.x * 64;
    const int tid = threadIdx.x;
    const int w = tid >> 6;
    const int l = tid & 63;

    for (int p = tid; p < 2048; p += 256) {
        int row = p >> 5, c = p & 31;
        int gr = m0 + row;
        uint4 v = make_uint4(0, 0, 0, 0);
        if (gr < M) v = (c < 16) ? xb4[gr * 16 + c] : xagg4[gr * 16 + (c - 16)];
        *(uint4*)&As[row][(c ^ (row & 7)) * 8] = v;
    }
    __syncthreads();

    const int fr = l & 15;
    const int kq = l >> 4;
    f32x4 acc[2][4] = {};
#pragma unroll
    for (int kt = 0; kt < 8; ++kt) {
        bf16x8 bfr[2];
#pragma unroll
        for (int ct = 0; ct < 2; ++ct) {
            int nn = w * 32 + ct * 16 + fr;
            bfr[ct] = *(const bf16x8*)&Bt1[nn * 256 + kt * 32 + kq * 8];
        }
        bf16x8 af[4];
#pragma unroll
        for (int rt = 0; rt < 4; ++rt) {
            int row = rt * 16 + fr;
            int c = (kt * 4 + kq) ^ (row & 7);
            af[rt] = *(bf16x8*)&As[row][c * 8];
        }
#pragma unroll
        for (int ct = 0; ct < 2; ++ct)
#pragma unroll
            for (int rt = 0; rt < 4; ++rt)
                acc[ct][rt] = __builtin_amdgcn_mfma_f32_16x16x32_bf16(af[rt], bfr[ct],
                                                                      acc[ct][rt], 0, 0, 0);
    }

#pragma unroll
    for (int ct = 0; ct < 2; ++ct) {
        int col = w * 32 + ct * 16 + fr;
        float bv = b1[col];
#pragma unroll
        for (int rt = 0; rt < 4; ++rt) {
#pragma unroll
            for (int j = 0; j < 4; ++j) {
                int row = m0 + rt * 16 + (l >> 4) * 4 + j;
                if (row < M) h1b[row * 128 + col] = f2bf(fmaxf(acc[ct][rt][j] + bv, 0.f));
            }
        }
    }
}

// ---------------- gemm2: [out | p2] = h1b @ Bt2^T (+b2 on out), K=128 ---------------
__global__ __launch_bounds__(256) void k_gemm2(const unsigned short* __restrict__ h1b,
                                               const unsigned short* __restrict__ Bt2,
                                               const float* __restrict__ b2,
                                               float* __restrict__ out,
                                               unsigned short* __restrict__ p2, int M) {
    __shared__ unsigned short As[64][128];
    const int m0 = blockIdx.x * 64;
    const int tid = threadIdx.x;
    const int w = tid >> 6;
    const int l = tid & 63;

    const uint4* A4 = (const uint4*)h1b;
    for (int p = tid; p < 1024; p += 256) {
        int row = p >> 4, c = p & 15;
        int gr = m0 + row;
        uint4 v = make_uint4(0, 0, 0, 0);
        if (gr < M) v = A4[gr * 16 + c];
        *(uint4*)&As[row][(c ^ (row & 7)) * 8] = v;
    }
    __syncthreads();

    const int fr = l & 15;
    const int kq = l >> 4;
    f32x4 acc[2][4] = {};
#pragma unroll
    for (int kt = 0; kt < 4; ++kt) {
        bf16x8 bfr[2];
#pragma unroll
        for (int ct = 0; ct < 2; ++ct) {
            int nn = w * 32 + ct * 16 + fr;
            bfr[ct] = *(const bf16x8*)&Bt2[nn * 128 + kt * 32 + kq * 8];
        }
        bf16x8 af[4];
#pragma unroll
        for (int rt = 0; rt < 4; ++rt) {
            int row = rt * 16 + fr;
            int c = (kt * 4 + kq) ^ (row & 7);
            af[rt] = *(bf16x8*)&As[row][c * 8];
        }
#pragma unroll
        for (int ct = 0; ct < 2; ++ct)
#pragma unroll
            for (int rt = 0; rt < 4; ++rt)
                acc[ct][rt] = __builtin_amdgcn_mfma_f32_16x16x32_bf16(af[rt], bfr[ct],
                                                                      acc[ct][rt], 0, 0, 0);
    }

#pragma unroll
    for (int ct = 0; ct < 2; ++ct) {
        int col = w * 32 + ct * 16 + fr;
        bool isS = col < 64;  // wave-uniform per 16-col tile
        float bv = isS ? b2[col] : 0.f;
#pragma unroll
        for (int rt = 0; rt < 4; ++rt) {
#pragma unroll
            for (int j = 0; j < 4; ++j) {
                int row = m0 + rt * 16 + (l >> 4) * 4 + j;
                if (row < M) {
                    float v = acc[ct][rt][j];
                    if (isS) out[row * 64 + col] = v + bv;
                    else p2[row * 64 + (col - 64)] = f2bf(v);
                }
            }
        }
    }
}

// ---------------- layer-2 aggregation: out += mean_neigh(p2) (64 ch bf16) ----------
// 8 groups of 8 lanes; each group gathers one 128B row via uint4 (8 rows/instr).
__global__ __launch_bounds__(256) void k_agg2_add(const unsigned int* __restrict__ p,
                                                  float* __restrict__ out,
                                                  const int* __restrict__ row_start,
                                                  const int* __restrict__ deg,
                                                  const int* __restrict__ csr, int n) {
    int gw = (blockIdx.x * 256 + threadIdx.x) >> 6;
    int lane = threadIdx.x & 63;
    if (gw >= n) return;
    int start = row_start[gw];
    int cnt = deg[gw];
    const int g = lane >> 3;
    const int cl = lane & 7;
    float a0 = 0.f, a1 = 0.f, a2 = 0.f, a3 = 0.f, a4 = 0.f, a5 = 0.f, a6 = 0.f, a7 = 0.f;
    int i = 0;
    for (; i + 16 <= cnt; i += 16) {
        int e0 = csr[start + i + g];
        int e1 = csr[start + i + 8 + g];
        uint4 v0 = *(const uint4*)&p[e0 * 32 + cl * 4];
        uint4 v1 = *(const uint4*)&p[e1 * 32 + cl * 4];
        a0 += bflo(v0.x) + bflo(v1.x); a1 += bfhi(v0.x) + bfhi(v1.x);
        a2 += bflo(v0.y) + bflo(v1.y); a3 += bfhi(v0.y) + bfhi(v1.y);
        a4 += bflo(v0.z) + bflo(v1.z); a5 += bfhi(v0.z) + bfhi(v1.z);
        a6 += bflo(v0.w) + bflo(v1.w); a7 += bfhi(v0.w) + bfhi(v1.w);
    }
    for (; i < cnt; i += 8) {
        int nbi = i + g;
        if (nbi < cnt) {
            int ia = csr[start + nbi];
            uint4 va = *(const uint4*)&p[ia * 32 + cl * 4];
            a0 += bflo(va.x); a1 += bfhi(va.x);
            a2 += bflo(va.y); a3 += bfhi(va.y);
            a4 += bflo(va.z); a5 += bfhi(va.z);
            a6 += bflo(va.w); a7 += bfhi(va.w);
        }
    }
    a0 += __shfl_xor(a0, 8); a0 += __shfl_xor(a0, 16); a0 += __shfl_xor(a0, 32);
    a1 += __shfl_xor(a1, 8); a1 += __shfl_xor(a1, 16); a1 += __shfl_xor(a1, 32);
    a2 += __shfl_xor(a2, 8); a2 += __shfl_xor(a2, 16); a2 += __shfl_xor(a2, 32);
    a3 += __shfl_xor(a3, 8); a3 += __shfl_xor(a3, 16); a3 += __shfl_xor(a3, 32);
    a4 += __shfl_xor(a4, 8); a4 += __shfl_xor(a4, 16); a4 += __shfl_xor(a4, 32);
    a5 += __shfl_xor(a5, 8); a5 += __shfl_xor(a5, 16); a5 += __shfl_xor(a5, 32);
    a6 += __shfl_xor(a6, 8); a6 += __shfl_xor(a6, 16); a6 += __shfl_xor(a6, 32);
    a7 += __shfl_xor(a7, 8); a7 += __shfl_xor(a7, 16); a7 += __shfl_xor(a7, 32);
    float inv = 1.0f / fmaxf((float)cnt, 1.0f);
    if (g == 0) {
        float4 oa = *(const float4*)&out[gw * 64 + cl * 8];
        float4 ob = *(const float4*)&out[gw * 64 + cl * 8 + 4];
        oa.x += inv * a0; oa.y += inv * a1; oa.z += inv * a2; oa.w += inv * a3;
        ob.x += inv * a4; ob.y += inv * a5; ob.z += inv * a6; ob.w += inv * a7;
        *(float4*)&out[gw * 64 + cl * 8] = oa;
        *(float4*)&out[gw * 64 + cl * 8 + 4] = ob;
    }
}

extern "C" void kernel_launch(void* const* d_in, const int* in_sizes, int n_in,
                              void* d_out, int out_size, void* d_ws, size_t ws_size,
                              hipStream_t stream) {
    const float* x   = (const float*)d_in[0];
    const int*   src = (const int*)d_in[1];
    const int*   dst = (const int*)d_in[2];
    const float* Ws1 = (const float*)d_in[3];
    const float* Wn1 = (const float*)d_in[4];
    const float* b1  = (const float*)d_in[5];
    const float* Ws2 = (const float*)d_in[6];
    const float* Wn2 = (const float*)d_in[7];
    const float* b2  = (const float*)d_in[8];
    float* out = (float*)d_out;
    const int N = in_sizes[0] / N_CH;  // 50000
    const int E = in_sizes[1];         // 800000

    // workspace layout (256B-aligned). rank dead after fill_csr; xagg aliases it.
    char* ws = (char*)d_ws;
    int* deg       = (int*)(ws + 0);          // N ints -> 200704
    int* row_start = (int*)(ws + 200704);     // N ints -> 401408
    int* bsum      = (int*)(ws + 401408);     // <=256 ints -> 402432
    int* csr_src   = (int*)(ws + 402432);     // E ints -> 3602432 (persists)
    int* rank      = (int*)(ws + 3602432);    // E ints (dead after fill_csr)
    unsigned short* xagg = (unsigned short*)(ws + 3602432);  // bf16 [N][128] (aliases rank)
    unsigned short* xb  = (unsigned short*)(ws + 16402432);  // bf16 [N][128] node-major
    unsigned short* h1b = (unsigned short*)(ws + 29202432);  // bf16 [N][128]
    unsigned short* p2  = (unsigned short*)(ws + 42002432);  // bf16 [N][64]
    unsigned short* Bt1 = (unsigned short*)(ws + 48402432);  // [128][256] 64KB
    unsigned short* Bt2 = (unsigned short*)(ws + 48467968);  // [128][128] 32KB

    const int eb = (E + 255) / 256;   // 3125
    const int nb = (N + 255) / 256;   // 196 (<= 256)
    const int ndeg4 = (N + 3) / 4;    // 12500
    const int nxq = N * 16;           // 800000
    const int nxb = (nxq + 255) / 256;  // 3125

    k_zero<<<(ndeg4 + 255) / 256, 256, 0, stream>>>((uint4*)deg, ndeg4);
    k_initdeg<<<192 + nxb + eb, 256, 0, stream>>>(x, Ws1, Wn1, Ws2, Wn2, Bt1, Bt2,
                                                  (uint4*)xb, nxq, nxb, dst, deg, rank, E);
    k_block_reduce<<<nb, 256, 0, stream>>>(deg, bsum, N);
    k_scan_final<<<nb, 256, 0, stream>>>(deg, bsum, row_start, N, nb);
    k_fill_csr<<<eb, 256, 0, stream>>>(src, dst, rank, row_start, csr_src, E);

    k_aggx<<<(N + 3) / 4, 256, 0, stream>>>((const uint4*)xb, (uint4*)xagg, row_start, deg,
                                            csr_src, N);

    const int gb = (N + 63) / 64;  // 782
    k_gemm1<<<gb, 256, 0, stream>>>((const uint4*)xb, (const uint4*)xagg, Bt1, b1, h1b, N);
    k_gemm2<<<gb, 256, 0, stream>>>(h1b, Bt2, b2, out, p2, N);
    k_agg2_add<<<(N + 3) / 4, 256, 0, stream>>>((const unsigned int*)p2, out, row_start, deg,
                                                csr_src, N);
}